// Round 14
// baseline (199.144 us; speedup 1.0000x reference)
//
#include <hip/hip_runtime.h>

#define B_  2
#define T_  2048
#define C_  1024
#define H_  16
#define D_  64
#define M_  (B_*T_)   // 4096
#define N1_ (3*C_)    // 3072

typedef short bf16x8 __attribute__((ext_vector_type(8)));
typedef short bf16x4 __attribute__((ext_vector_type(4)));
typedef float f32x4 __attribute__((ext_vector_type(4)));
typedef unsigned short u16;
typedef u16 u16x8 __attribute__((ext_vector_type(8)));

#define QSCALE 0.18033688011112042f   // (1/8) * log2(e)
#define C8     11.541560327111707f    // 8 * log2(e)

__device__ __forceinline__ u16 f2bf(float f) {
  unsigned u = __float_as_uint(f);
  u += 0x7FFFu + ((u >> 16) & 1u);
  return (u16)(u >> 16);
}

__device__ __forceinline__ void gload16(const void* g, void* l) {
  __builtin_amdgcn_global_load_lds((__attribute__((address_space(1))) void*)g,
                                   (__attribute__((address_space(3))) void*)l,
                                   16, 0, 0);
}

// ---------------- fp32 -> bf16 conversion ----------------
__global__ __launch_bounds__(256) void cvt_bf16(const float* __restrict__ in,
                                                u16* __restrict__ out, int n) {
  int i = (blockIdx.x * 256 + threadIdx.x) * 8;
  if (i >= n) return;
  float4 a = *(const float4*)(in + i);
  float4 b = *(const float4*)(in + i + 4);
  u16x8 o;
  o[0] = f2bf(a.x); o[1] = f2bf(a.y); o[2] = f2bf(a.z); o[3] = f2bf(a.w);
  o[4] = f2bf(b.x); o[5] = f2bf(b.y); o[6] = f2bf(b.z); o[7] = f2bf(b.w);
  *(u16x8*)(out + i) = o;
}

// ---------------- shared GEMM mainloop: C += A[M,K] * W[N,K]^T ----------------
__device__ __forceinline__ void gemm_core(const u16* __restrict__ A,
                                          const u16* __restrict__ W,
                                          u16* As, u16* Bs,
                                          f32x4 (&acc)[4][4],
                                          int m0, int n0, int K) {
  int tid = threadIdx.x;
  int lane = tid & 63, wid = tid >> 6;
  int wr = wid >> 1, wc = wid & 1;

  int arow = wid * 16 + (lane >> 2);
  int ag = lane & 3;
  int sg = ag ^ ((arow >> 1) & 3);
  const u16* aSrc0 = A + (m0 + arow) * K + sg * 8;
  const u16* aSrc1 = aSrc0 + 64 * K;
  const u16* bSrc0 = W + (n0 + arow) * K + sg * 8;
  const u16* bSrc1 = bSrc0 + 64 * K;
  u16* aDst0 = As + (wid * 16) * 32;
  u16* aDst1 = As + (64 + wid * 16) * 32;
  u16* bDst0 = Bs + (wid * 16) * 32;
  u16* bDst1 = Bs + (64 + wid * 16) * 32;

  int rg = lane >> 4;
  int aoff[4], boff[4];
#pragma unroll
  for (int m = 0; m < 4; ++m) {
    int row = wr * 64 + m * 16 + (lane & 15);
    aoff[m] = row * 32 + (rg ^ ((row >> 1) & 3)) * 8;
    row = wc * 64 + m * 16 + (lane & 15);
    boff[m] = row * 32 + (rg ^ ((row >> 1) & 3)) * 8;
  }

  for (int kt = 0; kt < K / 32; ++kt) {
    int k0 = kt * 32;
    __syncthreads();
    gload16(aSrc0 + k0, aDst0);
    gload16(aSrc1 + k0, aDst1);
    gload16(bSrc0 + k0, bDst0);
    gload16(bSrc1 + k0, bDst1);
    __syncthreads();

    bf16x8 af[4], bfr[4];
#pragma unroll
    for (int m = 0; m < 4; ++m) af[m] = *(const bf16x8*)(As + aoff[m]);
#pragma unroll
    for (int n = 0; n < 4; ++n) bfr[n] = *(const bf16x8*)(Bs + boff[n]);
#pragma unroll
    for (int m = 0; m < 4; ++m)
#pragma unroll
      for (int n = 0; n < 4; ++n)
        acc[m][n] = __builtin_amdgcn_mfma_f32_16x16x32_bf16(af[m], bfr[n], acc[m][n], 0, 0, 0);
  }
}

// ---------------- GEMM1: qkv = x @ W_attn^T + b; Q pre-scaled by log2e/8 ----------------
__global__ __launch_bounds__(256) void gemm_qkv(const u16* __restrict__ A,
                                                const u16* __restrict__ W,
                                                const float* __restrict__ bias,
                                                u16* __restrict__ Qb,
                                                u16* __restrict__ Kb,
                                                u16* __restrict__ Vt) {
  __shared__ __align__(16) u16 As[128 * 32];
  __shared__ __align__(16) u16 Bs[128 * 32];
  f32x4 acc[4][4] = {};
  int m0 = blockIdx.x * 128, n0 = blockIdx.y * 128;
  gemm_core(A, W, As, Bs, acc, m0, n0, C_);

  int lane = threadIdx.x & 63, wid = threadIdx.x >> 6;
  int wr = wid >> 1, wc = wid & 1;
  int rg = lane >> 4, cl = lane & 15;
#pragma unroll
  for (int n = 0; n < 4; ++n) {
    int gn = n0 + wc * 64 + n * 16 + cl;
    float bv = bias[gn];
    int seg = gn >> 10, cc = gn & 1023;
    int h = cc >> 6, d = cc & 63;
    float sc = (seg == 0) ? QSCALE : 1.0f;
#pragma unroll
    for (int m = 0; m < 4; ++m) {
#pragma unroll
      for (int r = 0; r < 4; ++r) {
        int gm = m0 + wr * 64 + m * 16 + rg * 4 + r;
        int b = gm >> 11, t = gm & 2047;
        u16 val = f2bf((acc[m][n][r] + bv) * sc);
        int bh = b * 16 + h;
        if (seg == 0)      Qb[(bh * 2048 + t) * 64 + d] = val;
        else if (seg == 1) Kb[(bh * 2048 + t) * 64 + d] = val;
        else               Vt[(bh * 64 + d) * 2048 + t] = val;
      }
    }
  }
}

// ---------------- GEMM2: out = y @ W_proj^T + b (fp32 out) ----------------
__global__ __launch_bounds__(256) void gemm_proj(const u16* __restrict__ A,
                                                 const u16* __restrict__ W,
                                                 const float* __restrict__ bias,
                                                 float* __restrict__ out) {
  __shared__ __align__(16) u16 As[128 * 32];
  __shared__ __align__(16) u16 Bs[128 * 32];
  f32x4 acc[4][4] = {};
  int m0 = blockIdx.x * 128, n0 = blockIdx.y * 128;
  gemm_core(A, W, As, Bs, acc, m0, n0, C_);

  int lane = threadIdx.x & 63, wid = threadIdx.x >> 6;
  int wr = wid >> 1, wc = wid & 1;
  int rg = lane >> 4, cl = lane & 15;
#pragma unroll
  for (int n = 0; n < 4; ++n) {
    int gn = n0 + wc * 64 + n * 16 + cl;
    float bv = bias[gn];
#pragma unroll
    for (int m = 0; m < 4; ++m) {
#pragma unroll
      for (int r = 0; r < 4; ++r) {
        int gm = m0 + wr * 64 + m * 16 + rg * 4 + r;
        out[gm * 1024 + gn] = acc[m][n][r] + bv;
      }
    }
  }
}

// ---------------- flash attention v14: 4-way split blocks (frh x kvh) ----------------
// v11/v12 computation verbatim, but each 32q x KV unit is a 256-thread block:
// wave (frh,kvh) = 16 q-rows x 32 kv-cols. Per-wave persistent state ~35 regs
// -> target VGPR <= 64 -> 8 waves/SIMD (32 waves/CU, the HW cap). Same bh/qwi
// mapping, same P-LDS swizzle, no mfma16, no K ping-pong. kvh=1 publishes
// partials; kvh=0 combines (exact: no-max softmax) and stores.
__global__ __launch_bounds__(256, 4) void attn_fwd(const u16* __restrict__ Qb,
                                                   const u16* __restrict__ Kb,
                                                   const u16* __restrict__ Vt,
                                                   u16* __restrict__ Yb) {
  __shared__ __align__(16) u16 Ps[4][16 * 64];   // per-wave P tile (own kv half used)
  __shared__ __align__(16) f32x4 Co[2][4][64];   // kvh=1 o partials, per frh
  __shared__ float Cl[2][64];                    // kvh=1 l partials
  int tid = threadIdx.x, lane = tid & 63, wid = tid >> 6;
  int cl = lane & 15, kg = lane >> 4;
  int kvh = wid & 1, frh = wid >> 1;
  int bid = blockIdx.x;
  int bh = bid & 31;                   // CU-local head (R4 locality)
  int qwi = 63 - (bid >> 5);           // heavy-first
  int qw0 = qwi * 32;
  int jmax = qwi >> 1;
  int fc0 = kvh * 2;                   // this wave's fc pair
  const u16* Qp = Qb + (size_t)bh * (2048 * 64);
  const u16* Kp = Kb + (size_t)bh * (2048 * 64);
  const u16* Vp = Vt + (size_t)bh * (64 * 2048);
  u16* Pw = Ps[wid];

  int kbase = cl * 64 + kg * 8 + fc0 * 1024;    // + fcl*1024 + j*4096 (+32 dk)
  int vbase = cl * 2048 + kvh * 32 + kg * 8;    // + dc*32768 + j*64

  // Q fragments (B-operand): q = qw0 + frh*16 + cl, d-slice dk*32 + kg*8
  bf16x8 qf[2];
#pragma unroll
  for (int dk = 0; dk < 2; ++dk)
    qf[dk] = *(const bf16x8*)(Qp + (qw0 + frh * 16 + cl) * 64 + dk * 32 + kg * 8);

  f32x4 o[4] = {};
  float lsum = 0.f;
  const f32x4 CINIT = {-C8, -C8, -C8, -C8};

  bool edgeMine = (fc0 <= ((qwi & 1) ? 3 : 1));  // kvh=1 idle on even-qwi edge

  for (int j = 0; j <= jmax; ++j) {
    bool edge = (j == jmax);
    if (edge && !edgeMine) continue;

    // K frags (die into S-MFMA)
    bf16x8 kf[2][2];
    const u16* Kj = Kp + j * 4096 + kbase;
#pragma unroll
    for (int fcl = 0; fcl < 2; ++fcl) {
      kf[fcl][0] = *(const bf16x8*)(Kj + fcl * 1024);
      kf[fcl][1] = *(const bf16x8*)(Kj + fcl * 1024 + 32);
    }
    // V frags: own kv half (issued early, used after softmax)
    bf16x8 vf[4];
    const u16* Vj = Vp + j * 64 + vbase;
#pragma unroll
    for (int dc = 0; dc < 4; ++dc)
      vf[dc] = *(const bf16x8*)(Vj + dc * 32768);

    // S^T = K Q^T - C8 : lane holds q = qw0+frh*16+cl, kv = (fc0+fcl)*16 + kg*4 + r
    f32x4 s[2];
#pragma unroll
    for (int fcl = 0; fcl < 2; ++fcl) {
      f32x4 z = CINIT;
      z = __builtin_amdgcn_mfma_f32_16x16x32_bf16(kf[fcl][0], qf[0], z, 0, 0, 0);
      z = __builtin_amdgcn_mfma_f32_16x16x32_bf16(kf[fcl][1], qf[1], z, 0, 0, 0);
      s[fcl] = z;
    }
    if (edge) {
      int qg = qw0 + frh * 16 + cl;
#pragma unroll
      for (int fcl = 0; fcl < 2; ++fcl)
#pragma unroll
        for (int r = 0; r < 4; ++r)
          if (j * 64 + (fc0 + fcl) * 16 + kg * 4 + r > qg) s[fcl][r] = -1e30f;
    }

    // P = exp2(S); lsum; write P (swizzled, own granules)
    int rowb = cl * 64;
#pragma unroll
    for (int fcl = 0; fcl < 2; ++fcl) {
      bf16x4 pw;
#pragma unroll
      for (int r = 0; r < 4; ++r) {
        float p = exp2f(s[fcl][r]);
        lsum += p;
        pw[r] = (short)f2bf(p);
      }
      int fc = fc0 + fcl;
      *(bf16x4*)(Pw + rowb + (((fc * 2 + (kg >> 1)) ^ (cl & 7)) * 8) + (kg & 1) * 4) = pw;
    }
    // P A-frag (own kv half) + PV
    bf16x8 pf = *(const bf16x8*)(Pw + rowb + (((kvh * 4 + kg) ^ (cl & 7)) * 8));
#pragma unroll
    for (int dc = 0; dc < 4; ++dc)
      o[dc] = __builtin_amdgcn_mfma_f32_16x16x32_bf16(pf, vf[dc], o[dc], 0, 0, 0);
  }

  // combine: kvh=1 publishes partials; kvh=0 reduces, normalizes, stores
  if (kvh == 1) {
    Cl[frh][lane] = lsum;
#pragma unroll
    for (int dc = 0; dc < 4; ++dc) Co[frh][dc][lane] = o[dc];
  }
  __syncthreads();
  if (kvh == 0) {
    int b = bh >> 4, h = bh & 15;
    float l = lsum + Cl[frh][lane];
#pragma unroll
    for (int dc = 0; dc < 4; ++dc) o[dc] += Co[frh][dc][lane];
    l += __shfl_xor(l, 16);
    l += __shfl_xor(l, 32);
    float linv = 1.f / l;
    float li[4];
#pragma unroll
    for (int r = 0; r < 4; ++r) li[r] = __shfl(linv, kg * 4 + r);
#pragma unroll
    for (int dc = 0; dc < 4; ++dc)
#pragma unroll
      for (int r = 0; r < 4; ++r) {
        int t = qw0 + frh * 16 + kg * 4 + r;
        int d = dc * 16 + cl;
        Yb[((size_t)(b * 2048 + t)) * 1024 + h * 64 + d] = f2bf(o[dc][r] * li[r]);
      }
  }
}

extern "C" void kernel_launch(void* const* d_in, const int* in_sizes, int n_in,
                              void* d_out, int out_size, void* d_ws, size_t ws_size,
                              hipStream_t stream) {
  const float* x  = (const float*)d_in[0];
  const float* Wa = (const float*)d_in[1];
  const float* ba = (const float*)d_in[2];
  const float* Wp = (const float*)d_in[3];
  const float* bp = (const float*)d_in[4];
  float* out = (float*)d_out;

  u16* xb  = (u16*)d_ws;
  u16* Wab = xb  + (size_t)M_ * C_;
  u16* Wpb = Wab + (size_t)N1_ * C_;
  u16* Qb  = Wpb + (size_t)C_ * C_;
  u16* Kb  = Qb  + (size_t)M_ * C_;
  u16* Vt  = Kb  + (size_t)M_ * C_;
  u16* Yb  = Vt  + (size_t)M_ * C_;

  cvt_bf16<<<(M_ * C_) / 2048, 256, 0, stream>>>(x, xb, M_ * C_);
  cvt_bf16<<<(N1_ * C_) / 2048, 256, 0, stream>>>(Wa, Wab, N1_ * C_);
  cvt_bf16<<<(C_ * C_) / 2048, 256, 0, stream>>>(Wp, Wpb, C_ * C_);
  gemm_qkv<<<dim3(M_ / 128, N1_ / 128), 256, 0, stream>>>(xb, Wab, ba, Qb, Kb, Vt);
  attn_fwd<<<2048, 256, 0, stream>>>(Qb, Kb, Vt, Yb);
  gemm_proj<<<dim3(M_ / 128, C_ / 128), 256, 0, stream>>>(Yb, Wpb, bp, out);
}

// Round 15
// 137.101 us; speedup vs baseline: 1.4525x; 1.4525x over previous
//
#include <hip/hip_runtime.h>
#include <hip/hip_bf16.h>

#define B_  2
#define T_  2048
#define C_  1024
#define H_  16
#define D_  64
#define M_  (B_*T_)   // 4096
#define N1_ (3*C_)    // 3072

typedef short bf16x8 __attribute__((ext_vector_type(8)));
typedef short bf16x4 __attribute__((ext_vector_type(4)));
typedef float f32x4 __attribute__((ext_vector_type(4)));
typedef unsigned short u16;
typedef u16 u16x8 __attribute__((ext_vector_type(8)));

#define QSCALE 0.18033688011112042f   // (1/8) * log2(e)
#define C8     11.541560327111707f    // 8 * log2(e)

__device__ __forceinline__ u16 f2bf(float f) {
  unsigned u = __float_as_uint(f);
  u += 0x7FFFu + ((u >> 16) & 1u);
  return (u16)(u >> 16);
}

__device__ __forceinline__ void gload16(const void* g, void* l) {
  __builtin_amdgcn_global_load_lds((__attribute__((address_space(1))) void*)g,
                                   (__attribute__((address_space(3))) void*)l,
                                   16, 0, 0);
}

// ---------------- fp32 -> bf16 conversion, 3 sources -> contiguous ws ----------------
__global__ __launch_bounds__(256) void cvt3(const float* __restrict__ x,
                                            const float* __restrict__ wa,
                                            const float* __restrict__ wp,
                                            u16* __restrict__ out) {
  int i = (blockIdx.x * 256 + threadIdx.x) * 8;
  const float* src;
  int off;
  if (i < M_ * C_)                 { src = x;  off = 0; }
  else if (i < M_ * C_ + N1_ * C_) { src = wa; off = M_ * C_; }
  else                             { src = wp; off = M_ * C_ + N1_ * C_; }
  float4 a = *(const float4*)(src + (i - off));
  float4 b = *(const float4*)(src + (i - off) + 4);
  u16x8 o;
  o[0] = f2bf(a.x); o[1] = f2bf(a.y); o[2] = f2bf(a.z); o[3] = f2bf(a.w);
  o[4] = f2bf(b.x); o[5] = f2bf(b.y); o[6] = f2bf(b.z); o[7] = f2bf(b.w);
  *(u16x8*)(out + i) = o;
}

// ---------------- shared GEMM mainloop: C += A[M,K] * W[N,K]^T ----------------
__device__ __forceinline__ void gemm_core(const u16* __restrict__ A,
                                          const u16* __restrict__ W,
                                          u16* As, u16* Bs,
                                          f32x4 (&acc)[4][4],
                                          int m0, int n0, int K) {
  int tid = threadIdx.x;
  int lane = tid & 63, wid = tid >> 6;
  int wr = wid >> 1, wc = wid & 1;

  int arow = wid * 16 + (lane >> 2);
  int ag = lane & 3;
  int sg = ag ^ ((arow >> 1) & 3);
  const u16* aSrc0 = A + (m0 + arow) * K + sg * 8;
  const u16* aSrc1 = aSrc0 + 64 * K;
  const u16* bSrc0 = W + (n0 + arow) * K + sg * 8;
  const u16* bSrc1 = bSrc0 + 64 * K;
  u16* aDst0 = As + (wid * 16) * 32;
  u16* aDst1 = As + (64 + wid * 16) * 32;
  u16* bDst0 = Bs + (wid * 16) * 32;
  u16* bDst1 = Bs + (64 + wid * 16) * 32;

  int rg = lane >> 4;
  int aoff[4], boff[4];
#pragma unroll
  for (int m = 0; m < 4; ++m) {
    int row = wr * 64 + m * 16 + (lane & 15);
    aoff[m] = row * 32 + (rg ^ ((row >> 1) & 3)) * 8;
    row = wc * 64 + m * 16 + (lane & 15);
    boff[m] = row * 32 + (rg ^ ((row >> 1) & 3)) * 8;
  }

  for (int kt = 0; kt < K / 32; ++kt) {
    int k0 = kt * 32;
    __syncthreads();
    gload16(aSrc0 + k0, aDst0);
    gload16(aSrc1 + k0, aDst1);
    gload16(bSrc0 + k0, bDst0);
    gload16(bSrc1 + k0, bDst1);
    __syncthreads();

    bf16x8 af[4], bfr[4];
#pragma unroll
    for (int m = 0; m < 4; ++m) af[m] = *(const bf16x8*)(As + aoff[m]);
#pragma unroll
    for (int n = 0; n < 4; ++n) bfr[n] = *(const bf16x8*)(Bs + boff[n]);
#pragma unroll
    for (int m = 0; m < 4; ++m)
#pragma unroll
      for (int n = 0; n < 4; ++n)
        acc[m][n] = __builtin_amdgcn_mfma_f32_16x16x32_bf16(af[m], bfr[n], acc[m][n], 0, 0, 0);
  }
}

// ---------------- GEMM1: qkv = x @ W_attn^T + b; Q pre-scaled by log2e/8 ----------------
__global__ __launch_bounds__(256) void gemm_qkv(const u16* __restrict__ A,
                                                const u16* __restrict__ W,
                                                const float* __restrict__ bias,
                                                u16* __restrict__ Qb,
                                                u16* __restrict__ Kb,
                                                u16* __restrict__ Vt) {
  __shared__ __align__(16) u16 As[128 * 32];
  __shared__ __align__(16) u16 Bs[128 * 32];
  f32x4 acc[4][4] = {};
  int m0 = blockIdx.x * 128, n0 = blockIdx.y * 128;
  gemm_core(A, W, As, Bs, acc, m0, n0, C_);

  int lane = threadIdx.x & 63, wid = threadIdx.x >> 6;
  int wr = wid >> 1, wc = wid & 1;
  int rg = lane >> 4, cl = lane & 15;
#pragma unroll
  for (int n = 0; n < 4; ++n) {
    int gn = n0 + wc * 64 + n * 16 + cl;
    float bv = bias[gn];
    int seg = gn >> 10, cc = gn & 1023;
    int h = cc >> 6, d = cc & 63;
    float sc = (seg == 0) ? QSCALE : 1.0f;
#pragma unroll
    for (int m = 0; m < 4; ++m) {
#pragma unroll
      for (int r = 0; r < 4; ++r) {
        int gm = m0 + wr * 64 + m * 16 + rg * 4 + r;
        int b = gm >> 11, t = gm & 2047;
        u16 val = f2bf((acc[m][n][r] + bv) * sc);
        int bh = b * 16 + h;
        if (seg == 0)      Qb[(bh * 2048 + t) * 64 + d] = val;
        else if (seg == 1) Kb[(bh * 2048 + t) * 64 + d] = val;
        else               Vt[(bh * 64 + d) * 2048 + t] = val;
      }
    }
  }
}

// ---------------- GEMM2: out = y @ W_proj^T + b (fp32 out) ----------------
__global__ __launch_bounds__(256) void gemm_proj(const u16* __restrict__ A,
                                                 const u16* __restrict__ W,
                                                 const float* __restrict__ bias,
                                                 float* __restrict__ out) {
  __shared__ __align__(16) u16 As[128 * 32];
  __shared__ __align__(16) u16 Bs[128 * 32];
  f32x4 acc[4][4] = {};
  int m0 = blockIdx.x * 128, n0 = blockIdx.y * 128;
  gemm_core(A, W, As, Bs, acc, m0, n0, C_);

  int lane = threadIdx.x & 63, wid = threadIdx.x >> 6;
  int wr = wid >> 1, wc = wid & 1;
  int rg = lane >> 4, cl = lane & 15;
#pragma unroll
  for (int n = 0; n < 4; ++n) {
    int gn = n0 + wc * 64 + n * 16 + cl;
    float bv = bias[gn];
#pragma unroll
    for (int m = 0; m < 4; ++m) {
#pragma unroll
      for (int r = 0; r < 4; ++r) {
        int gm = m0 + wr * 64 + m * 16 + rg * 4 + r;
        out[gm * 1024 + gn] = acc[m][n][r] + bv;
      }
    }
  }
}

// ---------------- flash attention v15: v12 + V ping-pong + paired bf16 cvt ---------
// v12 structure (kv-split 2-wave blocks, bh=bid&31 locality, K ping-pong,
// P-LDS swizzle). New: V frags also ping-pong (full tile-ahead prefetch ->
// both K and V latency hidden), and P packs via __float22bfloat162_rn
// (hardware v_cvt_pk_bf16_f32, RNE) instead of 3-op manual rounding.
__global__ __launch_bounds__(128, 2) void attn_fwd(const u16* __restrict__ Qb,
                                                   const u16* __restrict__ Kb,
                                                   const u16* __restrict__ Vt,
                                                   u16* __restrict__ Yb) {
  __shared__ __align__(16) u16 Ps[2][32 * 64];   // per-wave P tile
  __shared__ __align__(16) f32x4 Co[8][64];      // wave1 o partials
  __shared__ float Cl[2][64];                    // wave1 l partials
  int tid = threadIdx.x, lane = tid & 63, wid = tid >> 6;
  int cl = lane & 15, kg = lane >> 4;
  int bid = blockIdx.x;
  int bh = bid & 31;                   // CU-local head
  int qwi = 63 - (bid >> 5);           // heavy-first
  int qw0 = qwi * 32;
  int jmax = qwi >> 1;
  int fc0 = wid * 2;                   // this wave's fc pair
  const u16* Qp = Qb + (size_t)bh * (2048 * 64);
  const u16* Kp = Kb + (size_t)bh * (2048 * 64);
  const u16* Vp = Vt + (size_t)bh * (64 * 2048);
  u16* Pw = Ps[wid];

  int kbase = cl * 64 + kg * 8 + fc0 * 1024;    // + fcl*1024 + j*4096 (+32 dk)
  int vbase = cl * 2048 + wid * 32 + kg * 8;    // + dc*32768 + j*64

  // Q fragments (B-operand): q = qw0 + fr*16 + cl, d-slice dk*32 + kg*8
  bf16x8 qf[2][2];
#pragma unroll
  for (int fr = 0; fr < 2; ++fr)
#pragma unroll
    for (int dk = 0; dk < 2; ++dk)
      qf[fr][dk] = *(const bf16x8*)(Qp + (qw0 + fr * 16 + cl) * 64 + dk * 32 + kg * 8);

  f32x4 o[2][4] = {};
  float lsum[2] = {0.f, 0.f};
  const f32x4 CINIT = {-C8, -C8, -C8, -C8};

  auto LOADK = [&](bf16x8 (&kf)[2][2], int j) {
    const u16* Kj = Kp + j * 4096 + kbase;
#pragma unroll
    for (int fcl = 0; fcl < 2; ++fcl) {
      kf[fcl][0] = *(const bf16x8*)(Kj + fcl * 1024);
      kf[fcl][1] = *(const bf16x8*)(Kj + fcl * 1024 + 32);
    }
  };

  auto LOADV = [&](bf16x8 (&vf)[4], int j) {
    const u16* Vj = Vp + j * 64 + vbase;
#pragma unroll
    for (int dc = 0; dc < 4; ++dc)
      vf[dc] = *(const bf16x8*)(Vj + dc * 32768);
  };

  auto CORE = [&](bf16x8 (&kf)[2][2], bf16x8 (&vf)[4], int j, bool edge) {
    // S^T = K Q^T - C8 : lane holds q = fr*16+cl, kv = (fc0+fcl)*16 + kg*4 + r
    f32x4 s[2][2];
#pragma unroll
    for (int fcl = 0; fcl < 2; ++fcl)
#pragma unroll
      for (int fr = 0; fr < 2; ++fr) {
        f32x4 z = CINIT;
        z = __builtin_amdgcn_mfma_f32_16x16x32_bf16(kf[fcl][0], qf[fr][0], z, 0, 0, 0);
        z = __builtin_amdgcn_mfma_f32_16x16x32_bf16(kf[fcl][1], qf[fr][1], z, 0, 0, 0);
        s[fr][fcl] = z;
      }
    if (edge) {
#pragma unroll
      for (int fr = 0; fr < 2; ++fr) {
        int qg = qw0 + fr * 16 + cl;
#pragma unroll
        for (int fcl = 0; fcl < 2; ++fcl)
#pragma unroll
          for (int r = 0; r < 4; ++r)
            if (j * 64 + (fc0 + fcl) * 16 + kg * 4 + r > qg) s[fr][fcl][r] = -1e30f;
      }
    }

    // P = exp2(S); lsum; pack pairs via hw cvt_pk (RNE); write P half-tile
#pragma unroll
    for (int fr = 0; fr < 2; ++fr) {
      int rowb = (fr * 16 + cl) * 64;
#pragma unroll
      for (int fcl = 0; fcl < 2; ++fcl) {
        float p0 = exp2f(s[fr][fcl][0]);
        float p1 = exp2f(s[fr][fcl][1]);
        float p2 = exp2f(s[fr][fcl][2]);
        float p3 = exp2f(s[fr][fcl][3]);
        lsum[fr] += (p0 + p1) + (p2 + p3);
        union { bf16x4 v; __hip_bfloat162 h[2]; } pk;
        pk.h[0] = __float22bfloat162_rn(make_float2(p0, p1));
        pk.h[1] = __float22bfloat162_rn(make_float2(p2, p3));
        int fc = fc0 + fcl;
        *(bf16x4*)(Pw + rowb + (((fc * 2 + (kg >> 1)) ^ (cl & 7)) * 8) + (kg & 1) * 4) = pk.v;
      }
    }
    // P A-frags (own kv half) + PV
#pragma unroll
    for (int fr = 0; fr < 2; ++fr) {
      int rowb = (fr * 16 + cl) * 64;
      bf16x8 pf = *(const bf16x8*)(Pw + rowb + (((wid * 4 + kg) ^ (cl & 7)) * 8));
#pragma unroll
      for (int dc = 0; dc < 4; ++dc)
        o[fr][dc] = __builtin_amdgcn_mfma_f32_16x16x32_bf16(pf, vf[dc], o[fr][dc], 0, 0, 0);
    }
  };

  bool edgeMine = (fc0 <= ((qwi & 1) ? 3 : 1));  // wave1 idle on even-qwi edge

  bf16x8 kA[2][2], kB[2][2], vA[4], vB[4];
  LOADK(kA, 0); LOADV(vA, 0);
  if (jmax == 0) {
    if (edgeMine) CORE(kA, vA, 0, true);
  } else {
    LOADK(kB, 1); LOADV(vB, 1);
    int j = 0;
    while (j + 1 < jmax) {
      CORE(kA, vA, j, false);
      LOADK(kA, j + 2); LOADV(vA, j + 2);
      CORE(kB, vB, j + 1, false);
      int nx = (j + 3 <= jmax) ? j + 3 : jmax;
      LOADK(kB, nx); LOADV(vB, nx);
      j += 2;
    }
    if (j < jmax) { CORE(kA, vA, j, false); if (edgeMine) CORE(kB, vB, jmax, true); }
    else          { if (edgeMine) CORE(kA, vA, jmax, true); }
  }

  // combine: wave1 publishes partials; wave0 reduces, normalizes, stores
  if (wid == 1) {
#pragma unroll
    for (int fr = 0; fr < 2; ++fr) {
      Cl[fr][lane] = lsum[fr];
#pragma unroll
      for (int dc = 0; dc < 4; ++dc) Co[fr * 4 + dc][lane] = o[fr][dc];
    }
  }
  __syncthreads();
  if (wid == 0) {
    int b = bh >> 4, h = bh & 15;
#pragma unroll
    for (int fr = 0; fr < 2; ++fr) {
      float l = lsum[fr] + Cl[fr][lane];
#pragma unroll
      for (int dc = 0; dc < 4; ++dc) o[fr][dc] += Co[fr * 4 + dc][lane];
      l += __shfl_xor(l, 16);
      l += __shfl_xor(l, 32);
      float linv = 1.f / l;
      float li[4];
#pragma unroll
      for (int r = 0; r < 4; ++r) li[r] = __shfl(linv, kg * 4 + r);
#pragma unroll
      for (int dc = 0; dc < 4; ++dc)
#pragma unroll
        for (int r = 0; r < 4; ++r) {
          int t = qw0 + fr * 16 + kg * 4 + r;
          int d = dc * 16 + cl;
          Yb[((size_t)(b * 2048 + t)) * 1024 + h * 64 + d] = f2bf(o[fr][dc][r] * li[r]);
        }
    }
  }
}

extern "C" void kernel_launch(void* const* d_in, const int* in_sizes, int n_in,
                              void* d_out, int out_size, void* d_ws, size_t ws_size,
                              hipStream_t stream) {
  const float* x  = (const float*)d_in[0];
  const float* Wa = (const float*)d_in[1];
  const float* ba = (const float*)d_in[2];
  const float* Wp = (const float*)d_in[3];
  const float* bp = (const float*)d_in[4];
  float* out = (float*)d_out;

  u16* xb  = (u16*)d_ws;
  u16* Wab = xb  + (size_t)M_ * C_;
  u16* Wpb = Wab + (size_t)N1_ * C_;
  u16* Qb  = Wpb + (size_t)C_ * C_;
  u16* Kb  = Qb  + (size_t)M_ * C_;
  u16* Vt  = Kb  + (size_t)M_ * C_;
  u16* Yb  = Vt  + (size_t)M_ * C_;

  cvt3<<<(M_ * C_ + N1_ * C_ + C_ * C_) / 2048, 256, 0, stream>>>(x, Wa, Wp, xb);
  gemm_qkv<<<dim3(M_ / 128, N1_ / 128), 256, 0, stream>>>(xb, Wab, ba, Qb, Kb, Vt);
  attn_fwd<<<2048, 128, 0, stream>>>(Qb, Kb, Vt, Yb);
  gemm_proj<<<dim3(M_ / 128, C_ / 128), 256, 0, stream>>>(Yb, Wpb, bp, out);
}

// Round 17
// 136.772 us; speedup vs baseline: 1.4560x; 1.0024x over previous
//
#include <hip/hip_runtime.h>
#include <hip/hip_bf16.h>

#define B_  2
#define T_  2048
#define C_  1024
#define H_  16
#define D_  64
#define M_  (B_*T_)   // 4096
#define N1_ (3*C_)    // 3072

typedef short bf16x8 __attribute__((ext_vector_type(8)));
typedef short bf16x4 __attribute__((ext_vector_type(4)));
typedef float f32x4 __attribute__((ext_vector_type(4)));
typedef unsigned short u16;
typedef u16 u16x8 __attribute__((ext_vector_type(8)));

#define QSCALE 0.18033688011112042f   // (1/8) * log2(e)
#define C8     11.541560327111707f    // 8 * log2(e)

__device__ __forceinline__ u16 f2bf(float f) {
  unsigned u = __float_as_uint(f);
  u += 0x7FFFu + ((u >> 16) & 1u);
  return (u16)(u >> 16);
}

__device__ __forceinline__ void gload16(const void* g, void* l) {
  __builtin_amdgcn_global_load_lds((__attribute__((address_space(1))) void*)g,
                                   (__attribute__((address_space(3))) void*)l,
                                   16, 0, 0);
}

// ---------------- fp32 -> bf16 conversion, 3 sources -> contiguous ws ----------------
__global__ __launch_bounds__(256) void cvt3(const float* __restrict__ x,
                                            const float* __restrict__ wa,
                                            const float* __restrict__ wp,
                                            u16* __restrict__ out) {
  int i = (blockIdx.x * 256 + threadIdx.x) * 8;
  const float* src;
  int off;
  if (i < M_ * C_)                 { src = x;  off = 0; }
  else if (i < M_ * C_ + N1_ * C_) { src = wa; off = M_ * C_; }
  else                             { src = wp; off = M_ * C_ + N1_ * C_; }
  float4 a = *(const float4*)(src + (i - off));
  float4 b = *(const float4*)(src + (i - off) + 4);
  u16x8 o;
  o[0] = f2bf(a.x); o[1] = f2bf(a.y); o[2] = f2bf(a.z); o[3] = f2bf(a.w);
  o[4] = f2bf(b.x); o[5] = f2bf(b.y); o[6] = f2bf(b.z); o[7] = f2bf(b.w);
  *(u16x8*)(out + i) = o;
}

// ---------------- shared GEMM mainloop: C += A[M,K] * W[N,K]^T ----------------
__device__ __forceinline__ void gemm_core(const u16* __restrict__ A,
                                          const u16* __restrict__ W,
                                          u16* As, u16* Bs,
                                          f32x4 (&acc)[4][4],
                                          int m0, int n0, int K) {
  int tid = threadIdx.x;
  int lane = tid & 63, wid = tid >> 6;
  int wr = wid >> 1, wc = wid & 1;

  int arow = wid * 16 + (lane >> 2);
  int ag = lane & 3;
  int sg = ag ^ ((arow >> 1) & 3);
  const u16* aSrc0 = A + (m0 + arow) * K + sg * 8;
  const u16* aSrc1 = aSrc0 + 64 * K;
  const u16* bSrc0 = W + (n0 + arow) * K + sg * 8;
  const u16* bSrc1 = bSrc0 + 64 * K;
  u16* aDst0 = As + (wid * 16) * 32;
  u16* aDst1 = As + (64 + wid * 16) * 32;
  u16* bDst0 = Bs + (wid * 16) * 32;
  u16* bDst1 = Bs + (64 + wid * 16) * 32;

  int rg = lane >> 4;
  int aoff[4], boff[4];
#pragma unroll
  for (int m = 0; m < 4; ++m) {
    int row = wr * 64 + m * 16 + (lane & 15);
    aoff[m] = row * 32 + (rg ^ ((row >> 1) & 3)) * 8;
    row = wc * 64 + m * 16 + (lane & 15);
    boff[m] = row * 32 + (rg ^ ((row >> 1) & 3)) * 8;
  }

  for (int kt = 0; kt < K / 32; ++kt) {
    int k0 = kt * 32;
    __syncthreads();
    gload16(aSrc0 + k0, aDst0);
    gload16(aSrc1 + k0, aDst1);
    gload16(bSrc0 + k0, bDst0);
    gload16(bSrc1 + k0, bDst1);
    __syncthreads();

    bf16x8 af[4], bfr[4];
#pragma unroll
    for (int m = 0; m < 4; ++m) af[m] = *(const bf16x8*)(As + aoff[m]);
#pragma unroll
    for (int n = 0; n < 4; ++n) bfr[n] = *(const bf16x8*)(Bs + boff[n]);
#pragma unroll
    for (int m = 0; m < 4; ++m)
#pragma unroll
      for (int n = 0; n < 4; ++n)
        acc[m][n] = __builtin_amdgcn_mfma_f32_16x16x32_bf16(af[m], bfr[n], acc[m][n], 0, 0, 0);
  }
}

// ---------------- GEMM1: qkv = x @ W_attn^T + b; Q pre-scaled by log2e/8 ----------------
__global__ __launch_bounds__(256) void gemm_qkv(const u16* __restrict__ A,
                                                const u16* __restrict__ W,
                                                const float* __restrict__ bias,
                                                u16* __restrict__ Qb,
                                                u16* __restrict__ Kb,
                                                u16* __restrict__ Vt) {
  __shared__ __align__(16) u16 As[128 * 32];
  __shared__ __align__(16) u16 Bs[128 * 32];
  f32x4 acc[4][4] = {};
  int m0 = blockIdx.x * 128, n0 = blockIdx.y * 128;
  gemm_core(A, W, As, Bs, acc, m0, n0, C_);

  int lane = threadIdx.x & 63, wid = threadIdx.x >> 6;
  int wr = wid >> 1, wc = wid & 1;
  int rg = lane >> 4, cl = lane & 15;
#pragma unroll
  for (int n = 0; n < 4; ++n) {
    int gn = n0 + wc * 64 + n * 16 + cl;
    float bv = bias[gn];
    int seg = gn >> 10, cc = gn & 1023;
    int h = cc >> 6, d = cc & 63;
    float sc = (seg == 0) ? QSCALE : 1.0f;
#pragma unroll
    for (int m = 0; m < 4; ++m) {
#pragma unroll
      for (int r = 0; r < 4; ++r) {
        int gm = m0 + wr * 64 + m * 16 + rg * 4 + r;
        int b = gm >> 11, t = gm & 2047;
        u16 val = f2bf((acc[m][n][r] + bv) * sc);
        int bh = b * 16 + h;
        if (seg == 0)      Qb[(bh * 2048 + t) * 64 + d] = val;
        else if (seg == 1) Kb[(bh * 2048 + t) * 64 + d] = val;
        else               Vt[(bh * 64 + d) * 2048 + t] = val;
      }
    }
  }
}

// ---------------- GEMM2: out = y @ W_proj^T + b (fp32 out) ----------------
__global__ __launch_bounds__(256) void gemm_proj(const u16* __restrict__ A,
                                                 const u16* __restrict__ W,
                                                 const float* __restrict__ bias,
                                                 float* __restrict__ out) {
  __shared__ __align__(16) u16 As[128 * 32];
  __shared__ __align__(16) u16 Bs[128 * 32];
  f32x4 acc[4][4] = {};
  int m0 = blockIdx.x * 128, n0 = blockIdx.y * 128;
  gemm_core(A, W, As, Bs, acc, m0, n0, C_);

  int lane = threadIdx.x & 63, wid = threadIdx.x >> 6;
  int wr = wid >> 1, wc = wid & 1;
  int rg = lane >> 4, cl = lane & 15;
#pragma unroll
  for (int n = 0; n < 4; ++n) {
    int gn = n0 + wc * 64 + n * 16 + cl;
    float bv = bias[gn];
#pragma unroll
    for (int m = 0; m < 4; ++m) {
#pragma unroll
      for (int r = 0; r < 4; ++r) {
        int gm = m0 + wr * 64 + m * 16 + rg * 4 + r;
        out[gm * 1024 + gn] = acc[m][n][r] + bv;
      }
    }
  }
}

// ---------------- flash attention v17: kv-split + paired-tile pipeline ----------------
// v12/v15 body, but the main loop processes TILE PAIRS:
//   SEXP(j)->P0, SEXP(j+1)->P1, PV(j), PV(j+1)
// so each tile's P ds_write -> ds_read round trip (the unhideable ~240cy
// serial segment) is covered by the other tile's MFMA/exp work. Two P
// buffers per wave; K pair double-buffered (next pair's K issued after the
// SEXPs, where K regs are dead); V issued at body top (hidden by 2 SEXPs).
__global__ __launch_bounds__(128, 2) void attn_fwd(const u16* __restrict__ Qb,
                                                   const u16* __restrict__ Kb,
                                                   const u16* __restrict__ Vt,
                                                   u16* __restrict__ Yb) {
  __shared__ __align__(16) u16 Ps[2][2][32 * 64];  // [wave][buf]
  __shared__ __align__(16) f32x4 Co[8][64];        // wave1 o partials
  __shared__ float Cl[2][64];                      // wave1 l partials
  int tid = threadIdx.x, lane = tid & 63, wid = tid >> 6;
  int cl = lane & 15, kg = lane >> 4;
  int bid = blockIdx.x;
  int bh = bid & 31;                   // CU-local head
  int qwi = 63 - (bid >> 5);           // heavy-first
  int qw0 = qwi * 32;
  int jmax = qwi >> 1;
  int fc0 = wid * 2;                   // this wave's fc pair
  const u16* Qp = Qb + (size_t)bh * (2048 * 64);
  const u16* Kp = Kb + (size_t)bh * (2048 * 64);
  const u16* Vp = Vt + (size_t)bh * (64 * 2048);
  u16* P0 = Ps[wid][0];
  u16* P1 = Ps[wid][1];

  int kbase = cl * 64 + kg * 8 + fc0 * 1024;    // + fcl*1024 + j*4096 (+32 dk)
  int vbase = cl * 2048 + wid * 32 + kg * 8;    // + dc*32768 + j*64

  // Q fragments (B-operand): q = qw0 + fr*16 + cl, d-slice dk*32 + kg*8
  bf16x8 qf[2][2];
#pragma unroll
  for (int fr = 0; fr < 2; ++fr)
#pragma unroll
    for (int dk = 0; dk < 2; ++dk)
      qf[fr][dk] = *(const bf16x8*)(Qp + (qw0 + fr * 16 + cl) * 64 + dk * 32 + kg * 8);

  f32x4 o[2][4] = {};
  float lsum[2] = {0.f, 0.f};
  const f32x4 CINIT = {-C8, -C8, -C8, -C8};

  auto LOADK = [&](bf16x8 (&kf)[2][2], int j) {
    const u16* Kj = Kp + j * 4096 + kbase;
#pragma unroll
    for (int fcl = 0; fcl < 2; ++fcl) {
      kf[fcl][0] = *(const bf16x8*)(Kj + fcl * 1024);
      kf[fcl][1] = *(const bf16x8*)(Kj + fcl * 1024 + 32);
    }
  };

  auto LOADV = [&](bf16x8 (&vf)[4], int j) {
    const u16* Vj = Vp + j * 64 + vbase;
#pragma unroll
    for (int dc = 0; dc < 4; ++dc)
      vf[dc] = *(const bf16x8*)(Vj + dc * 32768);
  };

  // S = K Q^T - C8; mask (edge); P = exp2(S); pack; ds_write to Pw
  auto SEXP = [&](bf16x8 (&kf)[2][2], int j, bool edge, u16* Pw) {
    f32x4 s[2][2];
#pragma unroll
    for (int fcl = 0; fcl < 2; ++fcl)
#pragma unroll
      for (int fr = 0; fr < 2; ++fr) {
        f32x4 z = CINIT;
        z = __builtin_amdgcn_mfma_f32_16x16x32_bf16(kf[fcl][0], qf[fr][0], z, 0, 0, 0);
        z = __builtin_amdgcn_mfma_f32_16x16x32_bf16(kf[fcl][1], qf[fr][1], z, 0, 0, 0);
        s[fr][fcl] = z;
      }
    if (edge) {
#pragma unroll
      for (int fr = 0; fr < 2; ++fr) {
        int qg = qw0 + fr * 16 + cl;
#pragma unroll
        for (int fcl = 0; fcl < 2; ++fcl)
#pragma unroll
          for (int r = 0; r < 4; ++r)
            if (j * 64 + (fc0 + fcl) * 16 + kg * 4 + r > qg) s[fr][fcl][r] = -1e30f;
      }
    }
#pragma unroll
    for (int fr = 0; fr < 2; ++fr) {
      int rowb = (fr * 16 + cl) * 64;
#pragma unroll
      for (int fcl = 0; fcl < 2; ++fcl) {
        float p0 = exp2f(s[fr][fcl][0]);
        float p1 = exp2f(s[fr][fcl][1]);
        float p2 = exp2f(s[fr][fcl][2]);
        float p3 = exp2f(s[fr][fcl][3]);
        lsum[fr] += (p0 + p1) + (p2 + p3);
        union { bf16x4 v; __hip_bfloat162 h[2]; } pk;
        pk.h[0] = __float22bfloat162_rn(make_float2(p0, p1));
        pk.h[1] = __float22bfloat162_rn(make_float2(p2, p3));
        int fc = fc0 + fcl;
        *(bf16x4*)(Pw + rowb + (((fc * 2 + (kg >> 1)) ^ (cl & 7)) * 8) + (kg & 1) * 4) = pk.v;
      }
    }
  };

  auto PV = [&](bf16x8 (&vf)[4], u16* Pw) {
#pragma unroll
    for (int fr = 0; fr < 2; ++fr) {
      int rowb = (fr * 16 + cl) * 64;
      bf16x8 pf = *(const bf16x8*)(Pw + rowb + (((wid * 4 + kg) ^ (cl & 7)) * 8));
#pragma unroll
      for (int dc = 0; dc < 4; ++dc)
        o[fr][dc] = __builtin_amdgcn_mfma_f32_16x16x32_bf16(pf, vf[dc], o[fr][dc], 0, 0, 0);
    }
  };

  bool edgeMine = (fc0 <= ((qwi & 1) ? 3 : 1));  // wave1 idle on even-qwi edge

  bf16x8 k0[2][2], k1[2][2], v0[4], v1[4];
  LOADK(k0, 0);
  if (jmax >= 1) LOADK(k1, 1);

  int j = 0;
  while (j + 1 < jmax) {               // full (non-edge) pairs
    LOADV(v0, j);
    LOADV(v1, j + 1);
    SEXP(k0, j, false, P0);
    SEXP(k1, j + 1, false, P1);        // covers P0's write->read latency
    LOADK(k0, j + 2);                  // K regs dead here; hidden by 2x PV
    LOADK(k1, (j + 3 <= jmax) ? j + 3 : jmax);
    PV(v0, P0);                        // covers P1's write->read latency
    PV(v1, P1);
    j += 2;
  }
  if (j == jmax) {                     // single trailing (edge) tile
    if (edgeMine) { LOADV(v0, j); SEXP(k0, j, true, P0); PV(v0, P0); }
  } else {                             // j == jmax-1: full + edge pair
    LOADV(v0, j);
    SEXP(k0, j, false, P0);
    if (edgeMine) { LOADV(v1, j + 1); SEXP(k1, j + 1, true, P1); }
    PV(v0, P0);
    if (edgeMine) PV(v1, P1);
  }

  // combine: wave1 publishes partials; wave0 reduces, normalizes, stores
  if (wid == 1) {
#pragma unroll
    for (int fr = 0; fr < 2; ++fr) {
      Cl[fr][lane] = lsum[fr];
#pragma unroll
      for (int dc = 0; dc < 4; ++dc) Co[fr * 4 + dc][lane] = o[fr][dc];
    }
  }
  __syncthreads();
  if (wid == 0) {
    int b = bh >> 4, h = bh & 15;
#pragma unroll
    for (int fr = 0; fr < 2; ++fr) {
      float l = lsum[fr] + Cl[fr][lane];
#pragma unroll
      for (int dc = 0; dc < 4; ++dc) o[fr][dc] += Co[fr * 4 + dc][lane];
      l += __shfl_xor(l, 16);
      l += __shfl_xor(l, 32);
      float linv = 1.f / l;
      float li[4];
#pragma unroll
      for (int r = 0; r < 4; ++r) li[r] = __shfl(linv, kg * 4 + r);
#pragma unroll
      for (int dc = 0; dc < 4; ++dc)
#pragma unroll
        for (int r = 0; r < 4; ++r) {
          int t = qw0 + fr * 16 + kg * 4 + r;
          int d = dc * 16 + cl;
          Yb[((size_t)(b * 2048 + t)) * 1024 + h * 64 + d] = f2bf(o[fr][dc][r] * li[r]);
        }
    }
  }
}

extern "C" void kernel_launch(void* const* d_in, const int* in_sizes, int n_in,
                              void* d_out, int out_size, void* d_ws, size_t ws_size,
                              hipStream_t stream) {
  const float* x  = (const float*)d_in[0];
  const float* Wa = (const float*)d_in[1];
  const float* ba = (const float*)d_in[2];
  const float* Wp = (const float*)d_in[3];
  const float* bp = (const float*)d_in[4];
  float* out = (float*)d_out;

  u16* xb  = (u16*)d_ws;
  u16* Wab = xb  + (size_t)M_ * C_;
  u16* Wpb = Wab + (size_t)N1_ * C_;
  u16* Qb  = Wpb + (size_t)C_ * C_;
  u16* Kb  = Qb  + (size_t)M_ * C_;
  u16* Vt  = Kb  + (size_t)M_ * C_;
  u16* Yb  = Vt  + (size_t)M_ * C_;

  cvt3<<<(M_ * C_ + N1_ * C_ + C_ * C_) / 2048, 256, 0, stream>>>(x, Wa, Wp, xb);
  gemm_qkv<<<dim3(M_ / 128, N1_ / 128), 256, 0, stream>>>(xb, Wab, ba, Qb, Kb, Vt);
  attn_fwd<<<2048, 128, 0, stream>>>(Qb, Kb, Vt, Yb);
  gemm_proj<<<dim3(M_ / 128, C_ / 128), 256, 0, stream>>>(Yb, Wpb, bp, out);
}

// Round 18
// 135.935 us; speedup vs baseline: 1.4650x; 1.0062x over previous
//
#include <hip/hip_runtime.h>
#include <hip/hip_bf16.h>

#define B_  2
#define T_  2048
#define C_  1024
#define H_  16
#define D_  64
#define M_  (B_*T_)   // 4096
#define N1_ (3*C_)    // 3072

typedef short bf16x8 __attribute__((ext_vector_type(8)));
typedef short bf16x4 __attribute__((ext_vector_type(4)));
typedef float f32x4 __attribute__((ext_vector_type(4)));
typedef unsigned short u16;
typedef u16 u16x8 __attribute__((ext_vector_type(8)));

#define QSCALE 0.18033688011112042f   // (1/8) * log2(e)
#define C8     11.541560327111707f    // 8 * log2(e)

__device__ __forceinline__ u16 f2bf(float f) {
  unsigned u = __float_as_uint(f);
  u += 0x7FFFu + ((u >> 16) & 1u);
  return (u16)(u >> 16);
}

__device__ __forceinline__ void gload16(const void* g, void* l) {
  __builtin_amdgcn_global_load_lds((__attribute__((address_space(1))) void*)g,
                                   (__attribute__((address_space(3))) void*)l,
                                   16, 0, 0);
}

// ---------------- fp32 -> bf16 conversion, 3 sources -> contiguous ws ----------------
__global__ __launch_bounds__(256) void cvt3(const float* __restrict__ x,
                                            const float* __restrict__ wa,
                                            const float* __restrict__ wp,
                                            u16* __restrict__ out) {
  int i = (blockIdx.x * 256 + threadIdx.x) * 8;
  const float* src;
  int off;
  if (i < M_ * C_)                 { src = x;  off = 0; }
  else if (i < M_ * C_ + N1_ * C_) { src = wa; off = M_ * C_; }
  else                             { src = wp; off = M_ * C_ + N1_ * C_; }
  float4 a = *(const float4*)(src + (i - off));
  float4 b = *(const float4*)(src + (i - off) + 4);
  u16x8 o;
  o[0] = f2bf(a.x); o[1] = f2bf(a.y); o[2] = f2bf(a.z); o[3] = f2bf(a.w);
  o[4] = f2bf(b.x); o[5] = f2bf(b.y); o[6] = f2bf(b.z); o[7] = f2bf(b.w);
  *(u16x8*)(out + i) = o;
}

// ---------------- shared GEMM mainloop: C += A[M,K] * W[N,K]^T ----------------
__device__ __forceinline__ void gemm_core(const u16* __restrict__ A,
                                          const u16* __restrict__ W,
                                          u16* As, u16* Bs,
                                          f32x4 (&acc)[4][4],
                                          int m0, int n0, int K) {
  int tid = threadIdx.x;
  int lane = tid & 63, wid = tid >> 6;
  int wr = wid >> 1, wc = wid & 1;

  int arow = wid * 16 + (lane >> 2);
  int ag = lane & 3;
  int sg = ag ^ ((arow >> 1) & 3);
  const u16* aSrc0 = A + (m0 + arow) * K + sg * 8;
  const u16* aSrc1 = aSrc0 + 64 * K;
  const u16* bSrc0 = W + (n0 + arow) * K + sg * 8;
  const u16* bSrc1 = bSrc0 + 64 * K;
  u16* aDst0 = As + (wid * 16) * 32;
  u16* aDst1 = As + (64 + wid * 16) * 32;
  u16* bDst0 = Bs + (wid * 16) * 32;
  u16* bDst1 = Bs + (64 + wid * 16) * 32;

  int rg = lane >> 4;
  int aoff[4], boff[4];
#pragma unroll
  for (int m = 0; m < 4; ++m) {
    int row = wr * 64 + m * 16 + (lane & 15);
    aoff[m] = row * 32 + (rg ^ ((row >> 1) & 3)) * 8;
    row = wc * 64 + m * 16 + (lane & 15);
    boff[m] = row * 32 + (rg ^ ((row >> 1) & 3)) * 8;
  }

  for (int kt = 0; kt < K / 32; ++kt) {
    int k0 = kt * 32;
    __syncthreads();
    gload16(aSrc0 + k0, aDst0);
    gload16(aSrc1 + k0, aDst1);
    gload16(bSrc0 + k0, bDst0);
    gload16(bSrc1 + k0, bDst1);
    __syncthreads();

    bf16x8 af[4], bfr[4];
#pragma unroll
    for (int m = 0; m < 4; ++m) af[m] = *(const bf16x8*)(As + aoff[m]);
#pragma unroll
    for (int n = 0; n < 4; ++n) bfr[n] = *(const bf16x8*)(Bs + boff[n]);
#pragma unroll
    for (int m = 0; m < 4; ++m)
#pragma unroll
      for (int n = 0; n < 4; ++n)
        acc[m][n] = __builtin_amdgcn_mfma_f32_16x16x32_bf16(af[m], bfr[n], acc[m][n], 0, 0, 0);
  }
}

// ---------------- GEMM1: qkv = x @ W_attn^T + b; Q pre-scaled by log2e/8 ----------------
__global__ __launch_bounds__(256) void gemm_qkv(const u16* __restrict__ A,
                                                const u16* __restrict__ W,
                                                const float* __restrict__ bias,
                                                u16* __restrict__ Qb,
                                                u16* __restrict__ Kb,
                                                u16* __restrict__ Vt) {
  __shared__ __align__(16) u16 As[128 * 32];
  __shared__ __align__(16) u16 Bs[128 * 32];
  f32x4 acc[4][4] = {};
  int m0 = blockIdx.x * 128, n0 = blockIdx.y * 128;
  gemm_core(A, W, As, Bs, acc, m0, n0, C_);

  int lane = threadIdx.x & 63, wid = threadIdx.x >> 6;
  int wr = wid >> 1, wc = wid & 1;
  int rg = lane >> 4, cl = lane & 15;
#pragma unroll
  for (int n = 0; n < 4; ++n) {
    int gn = n0 + wc * 64 + n * 16 + cl;
    float bv = bias[gn];
    int seg = gn >> 10, cc = gn & 1023;
    int h = cc >> 6, d = cc & 63;
    float sc = (seg == 0) ? QSCALE : 1.0f;
#pragma unroll
    for (int m = 0; m < 4; ++m) {
#pragma unroll
      for (int r = 0; r < 4; ++r) {
        int gm = m0 + wr * 64 + m * 16 + rg * 4 + r;
        int b = gm >> 11, t = gm & 2047;
        u16 val = f2bf((acc[m][n][r] + bv) * sc);
        int bh = b * 16 + h;
        if (seg == 0)      Qb[(bh * 2048 + t) * 64 + d] = val;
        else if (seg == 1) Kb[(bh * 2048 + t) * 64 + d] = val;
        else               Vt[(bh * 64 + d) * 2048 + t] = val;
      }
    }
  }
}

// ---------------- GEMM2: out = y @ W_proj^T + b (fp32 out) ----------------
__global__ __launch_bounds__(256) void gemm_proj(const u16* __restrict__ A,
                                                 const u16* __restrict__ W,
                                                 const float* __restrict__ bias,
                                                 float* __restrict__ out) {
  __shared__ __align__(16) u16 As[128 * 32];
  __shared__ __align__(16) u16 Bs[128 * 32];
  f32x4 acc[4][4] = {};
  int m0 = blockIdx.x * 128, n0 = blockIdx.y * 128;
  gemm_core(A, W, As, Bs, acc, m0, n0, C_);

  int lane = threadIdx.x & 63, wid = threadIdx.x >> 6;
  int wr = wid >> 1, wc = wid & 1;
  int rg = lane >> 4, cl = lane & 15;
#pragma unroll
  for (int n = 0; n < 4; ++n) {
    int gn = n0 + wc * 64 + n * 16 + cl;
    float bv = bias[gn];
#pragma unroll
    for (int m = 0; m < 4; ++m) {
#pragma unroll
      for (int r = 0; r < 4; ++r) {
        int gm = m0 + wr * 64 + m * 16 + rg * 4 + r;
        out[gm * 1024 + gn] = acc[m][n][r] + bv;
      }
    }
  }
}

// ---------------- flash attention v18: paired pipeline + deep V prefetch ----------------
// v17 body, plus: V quad-buffered one full pair ahead (covers L3-latency V
// reads — K/V working set per XCD ~16MB >> 4MB L2, so re-reads are L3 hits
// at ~500-900cy); combine buffers aliased into Ps (LDS 25->16.5KB, 9
// blocks/CU cap so all 8 launched blocks stay resident).
__global__ __launch_bounds__(128, 2) void attn_fwd(const u16* __restrict__ Qb,
                                                   const u16* __restrict__ Kb,
                                                   const u16* __restrict__ Vt,
                                                   u16* __restrict__ Yb) {
  __shared__ __align__(16) u16 Ps[2][2][32 * 64];  // 16KB; aliased at epilogue
  int tid = threadIdx.x, lane = tid & 63, wid = tid >> 6;
  int cl = lane & 15, kg = lane >> 4;
  int bid = blockIdx.x;
  int bh = bid & 31;                   // CU-local head
  int qwi = 63 - (bid >> 5);           // heavy-first
  int qw0 = qwi * 32;
  int jmax = qwi >> 1;
  int fc0 = wid * 2;                   // this wave's fc pair
  const u16* Qp = Qb + (size_t)bh * (2048 * 64);
  const u16* Kp = Kb + (size_t)bh * (2048 * 64);
  const u16* Vp = Vt + (size_t)bh * (64 * 2048);
  u16* P0 = Ps[wid][0];
  u16* P1 = Ps[wid][1];

  int kbase = cl * 64 + kg * 8 + fc0 * 1024;    // + fcl*1024 + j*4096 (+32 dk)
  int vbase = cl * 2048 + wid * 32 + kg * 8;    // + dc*32768 + j*64

  // Q fragments (B-operand): q = qw0 + fr*16 + cl, d-slice dk*32 + kg*8
  bf16x8 qf[2][2];
#pragma unroll
  for (int fr = 0; fr < 2; ++fr)
#pragma unroll
    for (int dk = 0; dk < 2; ++dk)
      qf[fr][dk] = *(const bf16x8*)(Qp + (qw0 + fr * 16 + cl) * 64 + dk * 32 + kg * 8);

  f32x4 o[2][4] = {};
  float lsum[2] = {0.f, 0.f};
  const f32x4 CINIT = {-C8, -C8, -C8, -C8};

  auto LOADK = [&](bf16x8 (&kf)[2][2], int j) {
    const u16* Kj = Kp + j * 4096 + kbase;
#pragma unroll
    for (int fcl = 0; fcl < 2; ++fcl) {
      kf[fcl][0] = *(const bf16x8*)(Kj + fcl * 1024);
      kf[fcl][1] = *(const bf16x8*)(Kj + fcl * 1024 + 32);
    }
  };

  auto LOADV = [&](bf16x8 (&vf)[4], int j) {
    const u16* Vj = Vp + j * 64 + vbase;
#pragma unroll
    for (int dc = 0; dc < 4; ++dc)
      vf[dc] = *(const bf16x8*)(Vj + dc * 32768);
  };

  // S = K Q^T - C8; mask (edge); P = exp2(S); pack; ds_write to Pw
  auto SEXP = [&](bf16x8 (&kf)[2][2], int j, bool edge, u16* Pw) {
    f32x4 s[2][2];
#pragma unroll
    for (int fcl = 0; fcl < 2; ++fcl)
#pragma unroll
      for (int fr = 0; fr < 2; ++fr) {
        f32x4 z = CINIT;
        z = __builtin_amdgcn_mfma_f32_16x16x32_bf16(kf[fcl][0], qf[fr][0], z, 0, 0, 0);
        z = __builtin_amdgcn_mfma_f32_16x16x32_bf16(kf[fcl][1], qf[fr][1], z, 0, 0, 0);
        s[fr][fcl] = z;
      }
    if (edge) {
#pragma unroll
      for (int fr = 0; fr < 2; ++fr) {
        int qg = qw0 + fr * 16 + cl;
#pragma unroll
        for (int fcl = 0; fcl < 2; ++fcl)
#pragma unroll
          for (int r = 0; r < 4; ++r)
            if (j * 64 + (fc0 + fcl) * 16 + kg * 4 + r > qg) s[fr][fcl][r] = -1e30f;
      }
    }
#pragma unroll
    for (int fr = 0; fr < 2; ++fr) {
      int rowb = (fr * 16 + cl) * 64;
#pragma unroll
      for (int fcl = 0; fcl < 2; ++fcl) {
        float p0 = exp2f(s[fr][fcl][0]);
        float p1 = exp2f(s[fr][fcl][1]);
        float p2 = exp2f(s[fr][fcl][2]);
        float p3 = exp2f(s[fr][fcl][3]);
        lsum[fr] += (p0 + p1) + (p2 + p3);
        union { bf16x4 v; __hip_bfloat162 h[2]; } pk;
        pk.h[0] = __float22bfloat162_rn(make_float2(p0, p1));
        pk.h[1] = __float22bfloat162_rn(make_float2(p2, p3));
        int fc = fc0 + fcl;
        *(bf16x4*)(Pw + rowb + (((fc * 2 + (kg >> 1)) ^ (cl & 7)) * 8) + (kg & 1) * 4) = pk.v;
      }
    }
  };

  auto PV = [&](bf16x8 (&vf)[4], u16* Pw) {
#pragma unroll
    for (int fr = 0; fr < 2; ++fr) {
      int rowb = (fr * 16 + cl) * 64;
      bf16x8 pf = *(const bf16x8*)(Pw + rowb + (((wid * 4 + kg) ^ (cl & 7)) * 8));
#pragma unroll
      for (int dc = 0; dc < 4; ++dc)
        o[fr][dc] = __builtin_amdgcn_mfma_f32_16x16x32_bf16(pf, vf[dc], o[fr][dc], 0, 0, 0);
    }
  };

  bool edgeMine = (fc0 <= ((qwi & 1) ? 3 : 1));  // wave1 idle on even-qwi edge

  bf16x8 k0[2][2], k1[2][2], v0[4], v1[4], v2[4], v3[4];
  int j = 0;
  LOADK(k0, 0); LOADV(v0, 0);
  if (jmax >= 1) { LOADK(k1, 1); LOADV(v1, 1); }

  while (j + 3 < jmax) {               // two full pairs per iteration
    LOADV(v2, j + 2); LOADV(v3, j + 3);          // V one pair ahead
    SEXP(k0, j, false, P0);
    SEXP(k1, j + 1, false, P1);
    LOADK(k0, j + 2); LOADK(k1, j + 3);
    PV(v0, P0); PV(v1, P1);

    int n0 = (j + 4 <= jmax) ? j + 4 : jmax;
    int n1 = (j + 5 <= jmax) ? j + 5 : jmax;
    LOADV(v0, n0); LOADV(v1, n1);                // V one pair ahead
    SEXP(k0, j + 2, false, P0);
    SEXP(k1, j + 3, false, P1);
    LOADK(k0, n0); LOADK(k1, n1);
    PV(v2, P0); PV(v3, P1);
    j += 4;
  }
  int r = jmax - j + 1;                // 1..4 remaining tiles; k0/v0=j, k1/v1=j+1
  if (r == 1) {
    if (edgeMine) { SEXP(k0, j, true, P0); PV(v0, P0); }
  } else if (r == 2) {
    SEXP(k0, j, false, P0);
    if (edgeMine) SEXP(k1, j + 1, true, P1);
    PV(v0, P0);
    if (edgeMine) PV(v1, P1);
  } else if (r == 3) {
    LOADV(v2, j + 2);
    SEXP(k0, j, false, P0);
    SEXP(k1, j + 1, false, P1);
    LOADK(k0, j + 2);
    PV(v0, P0); PV(v1, P1);
    if (edgeMine) { SEXP(k0, j + 2, true, P0); PV(v2, P0); }
  } else {                             // r == 4
    LOADV(v2, j + 2); LOADV(v3, j + 3);
    SEXP(k0, j, false, P0);
    SEXP(k1, j + 1, false, P1);
    LOADK(k0, j + 2); LOADK(k1, j + 3);
    PV(v0, P0); PV(v1, P1);
    SEXP(k0, j + 2, false, P0);
    if (edgeMine) SEXP(k1, j + 3, true, P1);
    PV(v2, P0);
    if (edgeMine) PV(v3, P1);
  }

  // epilogue: combine via LDS aliased onto Ps (dead after main loop)
  __syncthreads();                      // all waves done with Ps
  f32x4* Co = (f32x4*)&Ps[0][0][0];     // [8][64] f32x4 = 8 KB (= Ps[0])
  float*  Cl = (float*)&Ps[1][0][0];    // [2][64] f32 = 512 B (in Ps[1])
  if (wid == 1) {
#pragma unroll
    for (int fr = 0; fr < 2; ++fr) {
      Cl[fr * 64 + lane] = lsum[fr];
#pragma unroll
      for (int dc = 0; dc < 4; ++dc) Co[(fr * 4 + dc) * 64 + lane] = o[fr][dc];
    }
  }
  __syncthreads();
  if (wid == 0) {
    int b = bh >> 4, h = bh & 15;
#pragma unroll
    for (int fr = 0; fr < 2; ++fr) {
      float l = lsum[fr] + Cl[fr * 64 + lane];
#pragma unroll
      for (int dc = 0; dc < 4; ++dc) o[fr][dc] += Co[(fr * 4 + dc) * 64 + lane];
      l += __shfl_xor(l, 16);
      l += __shfl_xor(l, 32);
      float linv = 1.f / l;
      float li[4];
#pragma unroll
      for (int r2 = 0; r2 < 4; ++r2) li[r2] = __shfl(linv, kg * 4 + r2);
#pragma unroll
      for (int dc = 0; dc < 4; ++dc)
#pragma unroll
        for (int r2 = 0; r2 < 4; ++r2) {
          int t = qw0 + fr * 16 + kg * 4 + r2;
          int d = dc * 16 + cl;
          Yb[((size_t)(b * 2048 + t)) * 1024 + h * 64 + d] = f2bf(o[fr][dc][r2] * li[r2]);
        }
    }
  }
}

extern "C" void kernel_launch(void* const* d_in, const int* in_sizes, int n_in,
                              void* d_out, int out_size, void* d_ws, size_t ws_size,
                              hipStream_t stream) {
  const float* x  = (const float*)d_in[0];
  const float* Wa = (const float*)d_in[1];
  const float* ba = (const float*)d_in[2];
  const float* Wp = (const float*)d_in[3];
  const float* bp = (const float*)d_in[4];
  float* out = (float*)d_out;

  u16* xb  = (u16*)d_ws;
  u16* Wab = xb  + (size_t)M_ * C_;
  u16* Wpb = Wab + (size_t)N1_ * C_;
  u16* Qb  = Wpb + (size_t)C_ * C_;
  u16* Kb  = Qb  + (size_t)M_ * C_;
  u16* Vt  = Kb  + (size_t)M_ * C_;
  u16* Yb  = Vt  + (size_t)M_ * C_;

  cvt3<<<(M_ * C_ + N1_ * C_ + C_ * C_) / 2048, 256, 0, stream>>>(x, Wa, Wp, xb);
  gemm_qkv<<<dim3(M_ / 128, N1_ / 128), 256, 0, stream>>>(xb, Wab, ba, Qb, Kb, Vt);
  attn_fwd<<<2048, 128, 0, stream>>>(Qb, Kb, Vt, Yb);
  gemm_proj<<<dim3(M_ / 128, C_ / 128), 256, 0, stream>>>(Yb, Wpb, bp, out);
}

// Round 19
// 116.596 us; speedup vs baseline: 1.7080x; 1.1659x over previous
//
#include <hip/hip_runtime.h>
#include <hip/hip_bf16.h>

#define B_  2
#define T_  2048
#define C_  1024
#define H_  16
#define D_  64
#define M_  (B_*T_)   // 4096
#define N1_ (3*C_)    // 3072

typedef short bf16x8 __attribute__((ext_vector_type(8)));
typedef short bf16x4 __attribute__((ext_vector_type(4)));
typedef float f32x4 __attribute__((ext_vector_type(4)));
typedef unsigned short u16;
typedef u16 u16x8 __attribute__((ext_vector_type(8)));

#define QSCALE 0.18033688011112042f   // (1/8) * log2(e)
#define C8     11.541560327111707f    // 8 * log2(e)

__device__ __forceinline__ u16 f2bf(float f) {
  unsigned u = __float_as_uint(f);
  u += 0x7FFFu + ((u >> 16) & 1u);
  return (u16)(u >> 16);
}

__device__ __forceinline__ void gload16(const void* g, void* l) {
  __builtin_amdgcn_global_load_lds((__attribute__((address_space(1))) void*)g,
                                   (__attribute__((address_space(3))) void*)l,
                                   16, 0, 0);
}

// ---------------- fp32 -> bf16 conversion, 3 sources -> contiguous ws ----------------
__global__ __launch_bounds__(256) void cvt3(const float* __restrict__ x,
                                            const float* __restrict__ wa,
                                            const float* __restrict__ wp,
                                            u16* __restrict__ out) {
  int i = (blockIdx.x * 256 + threadIdx.x) * 8;
  const float* src;
  int off;
  if (i < M_ * C_)                 { src = x;  off = 0; }
  else if (i < M_ * C_ + N1_ * C_) { src = wa; off = M_ * C_; }
  else                             { src = wp; off = M_ * C_ + N1_ * C_; }
  float4 a = *(const float4*)(src + (i - off));
  float4 b = *(const float4*)(src + (i - off) + 4);
  u16x8 o;
  o[0] = f2bf(a.x); o[1] = f2bf(a.y); o[2] = f2bf(a.z); o[3] = f2bf(a.w);
  o[4] = f2bf(b.x); o[5] = f2bf(b.y); o[6] = f2bf(b.z); o[7] = f2bf(b.w);
  *(u16x8*)(out + i) = o;
}

// ---------------- shared GEMM mainloop: C += A[M,K] * W[N,K]^T ----------------
__device__ __forceinline__ void gemm_core(const u16* __restrict__ A,
                                          const u16* __restrict__ W,
                                          u16* As, u16* Bs,
                                          f32x4 (&acc)[4][4],
                                          int m0, int n0, int K) {
  int tid = threadIdx.x;
  int lane = tid & 63, wid = tid >> 6;
  int wr = wid >> 1, wc = wid & 1;

  int arow = wid * 16 + (lane >> 2);
  int ag = lane & 3;
  int sg = ag ^ ((arow >> 1) & 3);
  const u16* aSrc0 = A + (m0 + arow) * K + sg * 8;
  const u16* aSrc1 = aSrc0 + 64 * K;
  const u16* bSrc0 = W + (n0 + arow) * K + sg * 8;
  const u16* bSrc1 = bSrc0 + 64 * K;
  u16* aDst0 = As + (wid * 16) * 32;
  u16* aDst1 = As + (64 + wid * 16) * 32;
  u16* bDst0 = Bs + (wid * 16) * 32;
  u16* bDst1 = Bs + (64 + wid * 16) * 32;

  int rg = lane >> 4;
  int aoff[4], boff[4];
#pragma unroll
  for (int m = 0; m < 4; ++m) {
    int row = wr * 64 + m * 16 + (lane & 15);
    aoff[m] = row * 32 + (rg ^ ((row >> 1) & 3)) * 8;
    row = wc * 64 + m * 16 + (lane & 15);
    boff[m] = row * 32 + (rg ^ ((row >> 1) & 3)) * 8;
  }

  for (int kt = 0; kt < K / 32; ++kt) {
    int k0 = kt * 32;
    __syncthreads();
    gload16(aSrc0 + k0, aDst0);
    gload16(aSrc1 + k0, aDst1);
    gload16(bSrc0 + k0, bDst0);
    gload16(bSrc1 + k0, bDst1);
    __syncthreads();

    bf16x8 af[4], bfr[4];
#pragma unroll
    for (int m = 0; m < 4; ++m) af[m] = *(const bf16x8*)(As + aoff[m]);
#pragma unroll
    for (int n = 0; n < 4; ++n) bfr[n] = *(const bf16x8*)(Bs + boff[n]);
#pragma unroll
    for (int m = 0; m < 4; ++m)
#pragma unroll
      for (int n = 0; n < 4; ++n)
        acc[m][n] = __builtin_amdgcn_mfma_f32_16x16x32_bf16(af[m], bfr[n], acc[m][n], 0, 0, 0);
  }
}

// ---------------- GEMM1: qkv = x @ W_attn^T + b; Q pre-scaled by log2e/8 ----------------
__global__ __launch_bounds__(256) void gemm_qkv(const u16* __restrict__ A,
                                                const u16* __restrict__ W,
                                                const float* __restrict__ bias,
                                                u16* __restrict__ Qb,
                                                u16* __restrict__ Kb,
                                                u16* __restrict__ Vt) {
  __shared__ __align__(16) u16 As[128 * 32];
  __shared__ __align__(16) u16 Bs[128 * 32];
  f32x4 acc[4][4] = {};
  int m0 = blockIdx.x * 128, n0 = blockIdx.y * 128;
  gemm_core(A, W, As, Bs, acc, m0, n0, C_);

  int lane = threadIdx.x & 63, wid = threadIdx.x >> 6;
  int wr = wid >> 1, wc = wid & 1;
  int rg = lane >> 4, cl = lane & 15;
#pragma unroll
  for (int n = 0; n < 4; ++n) {
    int gn = n0 + wc * 64 + n * 16 + cl;
    float bv = bias[gn];
    int seg = gn >> 10, cc = gn & 1023;
    int h = cc >> 6, d = cc & 63;
    float sc = (seg == 0) ? QSCALE : 1.0f;
#pragma unroll
    for (int m = 0; m < 4; ++m) {
#pragma unroll
      for (int r = 0; r < 4; ++r) {
        int gm = m0 + wr * 64 + m * 16 + rg * 4 + r;
        int b = gm >> 11, t = gm & 2047;
        u16 val = f2bf((acc[m][n][r] + bv) * sc);
        int bh = b * 16 + h;
        if (seg == 0)      Qb[(bh * 2048 + t) * 64 + d] = val;
        else if (seg == 1) Kb[(bh * 2048 + t) * 64 + d] = val;
        else               Vt[(bh * 64 + d) * 2048 + t] = val;
      }
    }
  }
}

// ---------------- GEMM2: out = y @ W_proj^T + b (fp32 out) ----------------
__global__ __launch_bounds__(256) void gemm_proj(const u16* __restrict__ A,
                                                 const u16* __restrict__ W,
                                                 const float* __restrict__ bias,
                                                 float* __restrict__ out) {
  __shared__ __align__(16) u16 As[128 * 32];
  __shared__ __align__(16) u16 Bs[128 * 32];
  f32x4 acc[4][4] = {};
  int m0 = blockIdx.x * 128, n0 = blockIdx.y * 128;
  gemm_core(A, W, As, Bs, acc, m0, n0, C_);

  int lane = threadIdx.x & 63, wid = threadIdx.x >> 6;
  int wr = wid >> 1, wc = wid & 1;
  int rg = lane >> 4, cl = lane & 15;
#pragma unroll
  for (int n = 0; n < 4; ++n) {
    int gn = n0 + wc * 64 + n * 16 + cl;
    float bv = bias[gn];
#pragma unroll
    for (int m = 0; m < 4; ++m) {
#pragma unroll
      for (int r = 0; r < 4; ++r) {
        int gm = m0 + wr * 64 + m * 16 + rg * 4 + r;
        out[gm * 1024 + gn] = acc[m][n][r] + bv;
      }
    }
  }
}

// ---------------- flash attention v19: 4-wave shared LDS-staged K/V ----------------
// Block = (bh, qt): 128 consecutive q-rows, 4 waves x 32 rows. K/V tiles
// [64x64] staged once per block via global_load_lds (pre-swizzled source,
// granule XOR (lane&7)^(lane>>3)), double-buffered, m97 2-barrier pattern.
// K/V VMEM traffic /4 vs per-wave frag loads; frag reads = swizzled
// ds_read_b128 (2-way conflict = free). Per-wave compute = proven R4 body
// (swapped QK^T, no-max softmax, per-wave P LDS). Grid 512: per-CU qt pair
// (x, 15-x) -> constant 34 tiles/CU, no drain tail.
__global__ __launch_bounds__(256, 2) void attn_fwd(const u16* __restrict__ Qb,
                                                   const u16* __restrict__ Kb,
                                                   const u16* __restrict__ Vt,
                                                   u16* __restrict__ Yb) {
  __shared__ __align__(16) u16 Ks[2][64 * 64];   // [buf][kv][d], swizzled
  __shared__ __align__(16) u16 Vs[2][64 * 64];   // [buf][d][kv], swizzled
  __shared__ __align__(16) u16 Ps[4][32 * 64];   // per-wave P tile
  int tid = threadIdx.x, lane = tid & 63, w = tid >> 6;
  int cl = lane & 15, kg = lane >> 4;
  int bid = blockIdx.x;
  int bh = bid & 31;                    // CU-local head (CU = bid%256 model)
  int i = bid >> 5;                     // [0,16)
  int qt = (i < 8) ? i : 23 - i;        // per-CU pair (x, 15-x): equal work
  int qb0 = qt * 128 + w * 32;          // this wave's first q row
  int jmaxw = (qb0 + 31) >> 6;          // wave's diagonal tile
  int jmaxb = 2 * qt + 1;               // block's last tile
  const u16* Qp = Qb + (size_t)bh * (2048 * 64);
  const u16* Kp = Kb + (size_t)bh * (2048 * 64);
  const u16* Vp = Vt + (size_t)bh * (64 * 2048);
  u16* Pw = Ps[w];

  // staging: wave w stages rows [16w,16w+16) of K and of V per tile.
  // dest is linear (gload16: uniform base + lane*16B); source pre-swizzled.
  int srow8 = lane >> 3;                        // row-within-8 group
  int sg = (lane & 7) ^ srow8;                  // swizzled source granule
  const u16* Ksrc = Kp + (w * 16 + srow8) * 64 + sg * 8;     // + j*4096 (+512 r=1)
  const u16* Vsrc = Vp + (w * 16 + srow8) * 2048 + sg * 8;   // + j*64 (+8*2048 r=1)

  // Q fragments (B-operand): q = qb0 + fr*16 + cl, d-slice dk*32 + kg*8
  bf16x8 qf[2][2];
#pragma unroll
  for (int fr = 0; fr < 2; ++fr)
#pragma unroll
    for (int dk = 0; dk < 2; ++dk)
      qf[fr][dk] = *(const bf16x8*)(Qp + (qb0 + fr * 16 + cl) * 64 + dk * 32 + kg * 8);

  f32x4 o[2][4] = {};
  float lsum[2] = {0.f, 0.f};
  const f32x4 CINIT = {-C8, -C8, -C8, -C8};

  auto STAGE = [&](int j, int buf) {
    u16* kd = &Ks[buf][w * 1024];
    u16* vd = &Vs[buf][w * 1024];
    const u16* ks = Ksrc + j * 4096;
    const u16* vs = Vsrc + j * 64;
    gload16(ks, kd);                    // K rows [16w,16w+8)
    gload16(ks + 512, kd + 512);        // K rows [16w+8,16w+16)
    gload16(vs, vd);                    // V rows [16w,16w+8)
    gload16(vs + 8 * 2048, vd + 512);   // V rows [16w+8,16w+16)
  };

  auto FULL = [&](int buf) {
    const u16* Kl = Ks[buf];
    const u16* Vl = Vs[buf];
    bf16x8 kf[4][2], vf[4][2];
#pragma unroll
    for (int fc = 0; fc < 4; ++fc) {
      int row = fc * 16 + cl;
      kf[fc][0] = *(const bf16x8*)(Kl + row * 64 + (((0 * 4 + kg) ^ (cl & 7)) * 8));
      kf[fc][1] = *(const bf16x8*)(Kl + row * 64 + (((1 * 4 + kg) ^ (cl & 7)) * 8));
    }
#pragma unroll
    for (int dc = 0; dc < 4; ++dc) {
      int row = dc * 16 + cl;
      vf[dc][0] = *(const bf16x8*)(Vl + row * 64 + (((0 * 4 + kg) ^ (cl & 7)) * 8));
      vf[dc][1] = *(const bf16x8*)(Vl + row * 64 + (((1 * 4 + kg) ^ (cl & 7)) * 8));
    }
    // S^T = K Q^T - C8 : lane holds q = fr*16+cl, kv = fc*16 + kg*4 + r
    f32x4 s[2][4];
#pragma unroll
    for (int fc = 0; fc < 4; ++fc)
#pragma unroll
      for (int fr = 0; fr < 2; ++fr) {
        f32x4 z = CINIT;
        z = __builtin_amdgcn_mfma_f32_16x16x32_bf16(kf[fc][0], qf[fr][0], z, 0, 0, 0);
        z = __builtin_amdgcn_mfma_f32_16x16x32_bf16(kf[fc][1], qf[fr][1], z, 0, 0, 0);
        s[fr][fc] = z;
      }
    // P = exp2(S); lsum; write P (per-wave swizzled tile)
#pragma unroll
    for (int fr = 0; fr < 2; ++fr) {
      int rowb = (fr * 16 + cl) * 64;
#pragma unroll
      for (int fc = 0; fc < 4; ++fc) {
        float p0 = exp2f(s[fr][fc][0]);
        float p1 = exp2f(s[fr][fc][1]);
        float p2 = exp2f(s[fr][fc][2]);
        float p3 = exp2f(s[fr][fc][3]);
        lsum[fr] += (p0 + p1) + (p2 + p3);
        union { bf16x4 v; __hip_bfloat162 h[2]; } pk;
        pk.h[0] = __float22bfloat162_rn(make_float2(p0, p1));
        pk.h[1] = __float22bfloat162_rn(make_float2(p2, p3));
        *(bf16x4*)(Pw + rowb + (((fc * 2 + (kg >> 1)) ^ (cl & 7)) * 8) + (kg & 1) * 4) = pk.v;
      }
    }
    // P A-frags + PV
    bf16x8 pf[2][2];
#pragma unroll
    for (int fr = 0; fr < 2; ++fr) {
      int rowb = (fr * 16 + cl) * 64;
      pf[fr][0] = *(const bf16x8*)(Pw + rowb + ((kg ^ (cl & 7)) * 8));
      pf[fr][1] = *(const bf16x8*)(Pw + rowb + (((kg + 4) ^ (cl & 7)) * 8));
    }
#pragma unroll
    for (int kv2 = 0; kv2 < 2; ++kv2)
#pragma unroll
      for (int dc = 0; dc < 4; ++dc) {
        o[0][dc] = __builtin_amdgcn_mfma_f32_16x16x32_bf16(pf[0][kv2], vf[dc][kv2], o[0][dc], 0, 0, 0);
        o[1][dc] = __builtin_amdgcn_mfma_f32_16x16x32_bf16(pf[1][kv2], vf[dc][kv2], o[1][dc], 0, 0, 0);
      }
  };

  auto EDGE = [&](int buf, int j) {
    const u16* Kl = Ks[buf];
    const u16* Vl = Vs[buf];
    int par = w & 1;
    int fcTop = par ? 3 : 1;
    int kvTop = par;
    bf16x8 kf[4][2], vf[4][2];
#pragma unroll
    for (int fc = 0; fc < 4; ++fc)
      if (fc <= fcTop) {
        int row = fc * 16 + cl;
        kf[fc][0] = *(const bf16x8*)(Kl + row * 64 + ((kg ^ (cl & 7)) * 8));
        kf[fc][1] = *(const bf16x8*)(Kl + row * 64 + (((4 + kg) ^ (cl & 7)) * 8));
      }
#pragma unroll
    for (int dc = 0; dc < 4; ++dc) {
      int row = dc * 16 + cl;
      vf[dc][0] = *(const bf16x8*)(Vl + row * 64 + ((kg ^ (cl & 7)) * 8));
      if (kvTop) vf[dc][1] = *(const bf16x8*)(Vl + row * 64 + (((4 + kg) ^ (cl & 7)) * 8));
    }
    f32x4 s[2][4];
#pragma unroll
    for (int fc = 0; fc < 4; ++fc)
      if (fc <= fcTop) {
#pragma unroll
        for (int fr = 0; fr < 2; ++fr) {
          f32x4 z = CINIT;
          z = __builtin_amdgcn_mfma_f32_16x16x32_bf16(kf[fc][0], qf[fr][0], z, 0, 0, 0);
          z = __builtin_amdgcn_mfma_f32_16x16x32_bf16(kf[fc][1], qf[fr][1], z, 0, 0, 0);
          s[fr][fc] = z;
        }
      }
#pragma unroll
    for (int fr = 0; fr < 2; ++fr) {
      int rowb = (fr * 16 + cl) * 64;
      int qg = qb0 + fr * 16 + cl;
#pragma unroll
      for (int fc = 0; fc < 4; ++fc) {
        bf16x4 pw;
        if (fc <= fcTop) {
#pragma unroll
          for (int r = 0; r < 4; ++r) {
            int kvg = j * 64 + fc * 16 + kg * 4 + r;
            float p = (kvg <= qg) ? exp2f(s[fr][fc][r]) : 0.f;
            lsum[fr] += p;
            pw[r] = (short)f2bf(p);
          }
        } else {
          pw[0] = 0; pw[1] = 0; pw[2] = 0; pw[3] = 0;
        }
        *(bf16x4*)(Pw + rowb + (((fc * 2 + (kg >> 1)) ^ (cl & 7)) * 8) + (kg & 1) * 4) = pw;
      }
    }
    bf16x8 pf[2][2];
#pragma unroll
    for (int fr = 0; fr < 2; ++fr) {
      int rowb = (fr * 16 + cl) * 64;
      pf[fr][0] = *(const bf16x8*)(Pw + rowb + ((kg ^ (cl & 7)) * 8));
      if (kvTop) pf[fr][1] = *(const bf16x8*)(Pw + rowb + (((kg + 4) ^ (cl & 7)) * 8));
    }
#pragma unroll
    for (int kv2 = 0; kv2 < 2; ++kv2)
      if (kv2 <= kvTop) {
#pragma unroll
        for (int dc = 0; dc < 4; ++dc) {
          o[0][dc] = __builtin_amdgcn_mfma_f32_16x16x32_bf16(pf[0][kv2], vf[dc][kv2], o[0][dc], 0, 0, 0);
          o[1][dc] = __builtin_amdgcn_mfma_f32_16x16x32_bf16(pf[1][kv2], vf[dc][kv2], o[1][dc], 0, 0, 0);
        }
      }
  };

  STAGE(0, 0);
  __syncthreads();
  int buf = 0;
  for (int j = 0; j <= jmaxb; ++j) {
    if (j < jmaxb) STAGE(j + 1, buf ^ 1);
    if (j < jmaxw)       FULL(buf);
    else if (j == jmaxw) EDGE(buf, j);
    __syncthreads();                    // stage drained + all waves done with buf
    buf ^= 1;
  }

  // epilogue: per-wave direct store (each wave owns complete rows)
  int b = bh >> 4, h = bh & 15;
#pragma unroll
  for (int fr = 0; fr < 2; ++fr) {
    float l = lsum[fr];
    l += __shfl_xor(l, 16);
    l += __shfl_xor(l, 32);
    float linv = 1.f / l;
    float li[4];
#pragma unroll
    for (int r = 0; r < 4; ++r) li[r] = __shfl(linv, kg * 4 + r);
#pragma unroll
    for (int dc = 0; dc < 4; ++dc)
#pragma unroll
      for (int r = 0; r < 4; ++r) {
        int t = qb0 + fr * 16 + kg * 4 + r;
        int d = dc * 16 + cl;
        Yb[((size_t)(b * 2048 + t)) * 1024 + h * 64 + d] = f2bf(o[fr][dc][r] * li[r]);
      }
  }
}

extern "C" void kernel_launch(void* const* d_in, const int* in_sizes, int n_in,
                              void* d_out, int out_size, void* d_ws, size_t ws_size,
                              hipStream_t stream) {
  const float* x  = (const float*)d_in[0];
  const float* Wa = (const float*)d_in[1];
  const float* ba = (const float*)d_in[2];
  const float* Wp = (const float*)d_in[3];
  const float* bp = (const float*)d_in[4];
  float* out = (float*)d_out;

  u16* xb  = (u16*)d_ws;
  u16* Wab = xb  + (size_t)M_ * C_;
  u16* Wpb = Wab + (size_t)N1_ * C_;
  u16* Qb  = Wpb + (size_t)C_ * C_;
  u16* Kb  = Qb  + (size_t)M_ * C_;
  u16* Vt  = Kb  + (size_t)M_ * C_;
  u16* Yb  = Vt  + (size_t)M_ * C_;

  cvt3<<<(M_ * C_ + N1_ * C_ + C_ * C_) / 2048, 256, 0, stream>>>(x, Wa, Wp, xb);
  gemm_qkv<<<dim3(M_ / 128, N1_ / 128), 256, 0, stream>>>(xb, Wab, ba, Qb, Kb, Vt);
  attn_fwd<<<512, 256, 0, stream>>>(Qb, Kb, Vt, Yb);
  gemm_proj<<<dim3(M_ / 128, C_ / 128), 256, 0, stream>>>(Yb, Wpb, bp, out);
}